// Round 1
// baseline (116.016 us; speedup 1.0000x reference)
//
#include <hip/hip_runtime.h>

#define GH 2048
#define GW 2048
#define OH 2046
#define OW 2046

constexpr int R       = 22;             // output rows per band (reads R+2 = 24 rows)
constexpr int BANDS   = 93;             // R * BANDS = 2046
constexpr int CTILES  = 33;             // 62 output cols per tile; 33*62 = 2046
constexpr int NWAVES  = CTILES * BANDS; // 3069 wave-tasks -> 12 waves/CU
constexpr int NBLOCKS = (NWAVES + 3) / 4; // 768 blocks -> exactly 3 blocks/CU
constexpr int PF      = 3;              // prefetch depth (rows in flight per wave)

__global__ __launch_bounds__(256)
void stencil_kernel(const float* __restrict__ E, const float* __restrict__ v,
                    const float* __restrict__ strain, float2* __restrict__ partials) {
    const int wslot = threadIdx.x >> 6;
    const int wid   = blockIdx.x * 4 + wslot;
    const int lane  = threadIdx.x & 63;

    float acc = 0.f, eacc = 0.f;

    if (wid < NWAVES) {                       // inactive waves still reach the barrier
        const int tile = wid % CTILES;
        const int band = wid / CTILES;
        const int col  = tile * 62 + lane;    // max = 32*62+63 = 2047: in bounds
        const int row0 = band * R;            // reads rows row0 .. row0+R+1 (max 2047)

        // exactly-once ownership for the E-mean over the full 2048^2 grid
        const bool eown_col = (lane < 62) || (tile == CTILES - 1);
        const int  own_rows = (band == BANDS - 1) ? R + 2 : R;
        const bool out_ok   = (lane < 62);

        // rolling 3-row state
        float he0=0,he1=0,he2=0;        // horizontal 3-sum of E
        float hxx0=0,hxx1=0,hxx2=0;     // horizontal 3-sum of s_xx
        float hxy0=0,hxy1=0,hxy2=0;     // horizontal 3-sum of s_xy
        float dxy0=0,dxy1=0,dxy2=0;     // s_xy(c) - s_xy(c+2) per row
        float dyy0=0,dyy1=0,dyy2=0;     // s_yy(c) - s_yy(c+2) per row

        // depth-PF prefetch buffers (register-resident after full unroll)
        float eb[PF], vb[PF], xxb[PF], yyb[PF], xyb[PF];
        int idx = row0 * GW + col;
        #pragma unroll
        for (int p = 0; p < PF; ++p) {
            const int j = idx + p * GW;
            eb[p]  = E[j];
            vb[p]  = v[j];
            xxb[p] = strain[3 * j + 0];
            yyb[p] = strain[3 * j + 1];
            xyb[p] = strain[3 * j + 2];
        }

        #pragma unroll
        for (int k = 0; k < R + 2; ++k) {
            const int s = k % PF;             // static after unroll
            const float e   = eb[s];
            const float vv  = vb[s];
            const float exx = xxb[s];
            const float eyy = yyb[s];
            const float exy = xyb[s];
            if (k + PF < R + 2) {             // prefetch row k+PF into the freed slot
                const int j = idx + PF * GW;
                eb[s]  = E[j];
                vb[s]  = v[j];
                xxb[s] = strain[3 * j + 0];
                yyb[s] = strain[3 * j + 1];
                xyb[s] = strain[3 * j + 2];
            }
            idx += GW;

            if (eown_col && k < own_rows) eacc += e;

            const float frac = e / (1.f - vv * vv);
            const float sx  = (exx + vv * eyy) * frac;
            const float sy_ = (vv * exx + eyy) * frac;
            const float sz_ = exy * (1.f - vv) * 0.5f * frac;

            const float e1 = __shfl_down(e,   1, 64), e2 = __shfl_down(e,   2, 64);
            const float x1 = __shfl_down(sx,  1, 64), x2 = __shfl_down(sx,  2, 64);
            const float z1 = __shfl_down(sz_, 1, 64), z2 = __shfl_down(sz_, 2, 64);
            const float y2 = __shfl_down(sy_, 2, 64);

            he0=he1;   he1=he2;   he2  = e   + e1 + e2;
            hxx0=hxx1; hxx1=hxx2; hxx2 = sx  + x1 + x2;
            hxy0=hxy1; hxy1=hxy2; hxy2 = sz_ + z1 + z2;
            dxy0=dxy1; dxy1=dxy2; dxy2 = sz_ - z2;
            dyy0=dyy1; dyy1=dyy2; dyy2 = sy_ - y2;

            if (k >= 2) {                     // emit output row (row0 + k - 2)
                const float fx = (hxx2 - hxx0) + (dxy0 + dxy1 + dxy2);
                const float fy = (dyy0 + dyy1 + dyy2) + (hxy2 - hxy0);
                const float inv = 1.f / (he0 + he1 + he2);
                const float c = fabsf(fx * inv) + fabsf(fy * inv);
                acc += out_ok ? c : 0.f;
            }
        }
    }

    // intra-wave reduction
    #pragma unroll
    for (int off = 32; off > 0; off >>= 1) {
        acc  += __shfl_down(acc,  off, 64);
        eacc += __shfl_down(eacc, off, 64);
    }
    // block-level reduction: one float2 per block -> finalize reads 6 KB not 49 KB
    __shared__ float sred[4][2];
    if (lane == 0) { sred[wslot][0] = acc; sred[wslot][1] = eacc; }
    __syncthreads();
    if (threadIdx.x == 0) {
        partials[blockIdx.x] =
            make_float2(sred[0][0] + sred[1][0] + sred[2][0] + sred[3][0],
                        sred[0][1] + sred[1][1] + sred[2][1] + sred[3][1]);
    }
}

__global__ __launch_bounds__(256)
void finalize_kernel(const float2* __restrict__ partials, float* __restrict__ out) {
    __shared__ double sacc[4][2];
    double a = 0.0, e = 0.0;
    #pragma unroll
    for (int i = threadIdx.x; i < NBLOCKS; i += 256) {   // exactly 3 iterations
        float2 p = partials[i];
        a += (double)p.x;
        e += (double)p.y;
    }
    #pragma unroll
    for (int off = 32; off > 0; off >>= 1) {
        a += __shfl_down(a, off, 64);
        e += __shfl_down(e, off, 64);
    }
    const int wave = threadIdx.x >> 6;
    if ((threadIdx.x & 63) == 0) { sacc[wave][0] = a; sacc[wave][1] = e; }
    __syncthreads();
    if (threadIdx.x == 0) {
        double A    = sacc[0][0] + sacc[1][0] + sacc[2][0] + sacc[3][0];
        double Esum = sacc[0][1] + sacc[1][1] + sacc[2][1] + sacc[3][1];
        double M = (double)OH * (double)OW;
        double loss_xy = A / M;
        double loss_e  = fabs(Esum / ((double)GH * (double)GW) - 1.0) / 100.0;
        out[0] = (float)(loss_xy + loss_e);
    }
}

extern "C" void kernel_launch(void* const* d_in, const int* in_sizes, int n_in,
                              void* d_out, int out_size, void* d_ws, size_t ws_size,
                              hipStream_t stream) {
    const float* E      = (const float*)d_in[0];
    const float* v      = (const float*)d_in[1];
    const float* strain = (const float*)d_in[2];
    float* out = (float*)d_out;
    float2* partials = (float2*)d_ws;

    hipLaunchKernelGGL(stencil_kernel, dim3(NBLOCKS), dim3(256), 0, stream,
                       E, v, strain, partials);
    hipLaunchKernelGGL(finalize_kernel, dim3(1), dim3(256), 0, stream, partials, out);
}

// Round 2
// 111.936 us; speedup vs baseline: 1.0364x; 1.0364x over previous
//
#include <hip/hip_runtime.h>

#define GH 2048
#define GW 2048
#define OH 2046
#define OW 2046

constexpr int R       = 11;               // output rows per band (reads R+2 = 13 rows)
constexpr int BANDS   = 186;              // R * BANDS = 2046
constexpr int CTILES  = 33;               // 62 output cols per tile; 33*62 = 2046
constexpr int NWAVES  = CTILES * BANDS;   // 6138 wave-tasks -> 24 waves/CU
constexpr int NBLOCKS = (NWAVES + 3) / 4; // 1535 blocks -> <=6 blocks/CU, no tail
constexpr int PF      = 3;                // prefetch depth (rows in flight per wave)

// band-major wid decomposition: the 4 waves of one block are 4 vertically
// adjacent bands of the SAME column tile -> the 2-row halos between them are
// fetched nearly simultaneously on the same CU (L1/L2 hit, not HBM re-read).
__global__ __launch_bounds__(256)
void stencil_kernel(const float* __restrict__ E, const float* __restrict__ v,
                    const float* __restrict__ strain, float2* __restrict__ partials) {
    const int wslot = threadIdx.x >> 6;
    const int wid   = blockIdx.x * 4 + wslot;
    const int lane  = threadIdx.x & 63;

    float acc = 0.f, eacc = 0.f;

    if (wid < NWAVES) {                     // inactive waves still reach the barrier
        const int band = wid % BANDS;       // band-major: consecutive wids = stacked bands
        const int tile = wid / BANDS;
        const int col  = tile * 62 + lane;  // max = 32*62+63 = 2047: in bounds
        const int row0 = band * R;          // reads rows row0 .. row0+R+1 (max 2047)

        // exactly-once ownership for the E-mean over the full 2048^2 grid
        const bool eown_col = (lane < 62) || (tile == CTILES - 1);
        const int  own_rows = (band == BANDS - 1) ? R + 2 : R;
        const bool out_ok   = (lane < 62);

        // rolling 3-row state
        float he0=0,he1=0,he2=0;        // horizontal 3-sum of E
        float hxx0=0,hxx1=0,hxx2=0;     // horizontal 3-sum of s_xx
        float hxy0=0,hxy1=0,hxy2=0;     // horizontal 3-sum of s_xy
        float dxy0=0,dxy1=0,dxy2=0;     // s_xy(c) - s_xy(c+2) per row
        float dyy0=0,dyy1=0,dyy2=0;     // s_yy(c) - s_yy(c+2) per row

        // depth-PF prefetch buffers (register-resident after full unroll)
        float eb[PF], vb[PF], xxb[PF], yyb[PF], xyb[PF];
        int idx = row0 * GW + col;
        #pragma unroll
        for (int p = 0; p < PF; ++p) {
            const int j = idx + p * GW;
            eb[p]  = E[j];
            vb[p]  = v[j];
            xxb[p] = strain[3 * j + 0];
            yyb[p] = strain[3 * j + 1];
            xyb[p] = strain[3 * j + 2];
        }

        #pragma unroll
        for (int k = 0; k < R + 2; ++k) {
            const int s = k % PF;           // static after full unroll (no scratch)
            const float e   = eb[s];
            const float vv  = vb[s];
            const float exx = xxb[s];
            const float eyy = yyb[s];
            const float exy = xyb[s];
            if (k + PF < R + 2) {           // prefetch row k+PF into the freed slot
                const int j = idx + PF * GW;
                eb[s]  = E[j];
                vb[s]  = v[j];
                xxb[s] = strain[3 * j + 0];
                yyb[s] = strain[3 * j + 1];
                xyb[s] = strain[3 * j + 2];
            }
            idx += GW;

            if (eown_col && k < own_rows) eacc += e;

            const float frac = e / (1.f - vv * vv);
            const float sx  = (exx + vv * eyy) * frac;
            const float sy_ = (vv * exx + eyy) * frac;
            const float sz_ = exy * (1.f - vv) * 0.5f * frac;

            const float e1 = __shfl_down(e,   1, 64), e2 = __shfl_down(e,   2, 64);
            const float x1 = __shfl_down(sx,  1, 64), x2 = __shfl_down(sx,  2, 64);
            const float z1 = __shfl_down(sz_, 1, 64), z2 = __shfl_down(sz_, 2, 64);
            const float y2 = __shfl_down(sy_, 2, 64);

            he0=he1;   he1=he2;   he2  = e   + e1 + e2;
            hxx0=hxx1; hxx1=hxx2; hxx2 = sx  + x1 + x2;
            hxy0=hxy1; hxy1=hxy2; hxy2 = sz_ + z1 + z2;
            dxy0=dxy1; dxy1=dxy2; dxy2 = sz_ - z2;
            dyy0=dyy1; dyy1=dyy2; dyy2 = sy_ - y2;

            if (k >= 2) {                   // emit output row (row0 + k - 2)
                const float fx = (hxx2 - hxx0) + (dxy0 + dxy1 + dxy2);
                const float fy = (dyy0 + dyy1 + dyy2) + (hxy2 - hxy0);
                const float inv = 1.f / (he0 + he1 + he2);
                const float c = fabsf(fx * inv) + fabsf(fy * inv);
                acc += out_ok ? c : 0.f;
            }
        }
    }

    // intra-wave reduction
    #pragma unroll
    for (int off = 32; off > 0; off >>= 1) {
        acc  += __shfl_down(acc,  off, 64);
        eacc += __shfl_down(eacc, off, 64);
    }
    // block-level reduction: one float2 per block -> finalize reads 12 KB not 49 KB
    __shared__ float sred[4][2];
    if (lane == 0) { sred[wslot][0] = acc; sred[wslot][1] = eacc; }
    __syncthreads();
    if (threadIdx.x == 0) {
        partials[blockIdx.x] =
            make_float2(sred[0][0] + sred[1][0] + sred[2][0] + sred[3][0],
                        sred[0][1] + sred[1][1] + sred[2][1] + sred[3][1]);
    }
}

__global__ __launch_bounds__(256)
void finalize_kernel(const float2* __restrict__ partials, float* __restrict__ out) {
    __shared__ double sacc[4][2];
    double a = 0.0, e = 0.0;
    for (int i = threadIdx.x; i < NBLOCKS; i += 256) {   // 6 iterations
        float2 p = partials[i];
        a += (double)p.x;
        e += (double)p.y;
    }
    #pragma unroll
    for (int off = 32; off > 0; off >>= 1) {
        a += __shfl_down(a, off, 64);
        e += __shfl_down(e, off, 64);
    }
    const int wave = threadIdx.x >> 6;
    if ((threadIdx.x & 63) == 0) { sacc[wave][0] = a; sacc[wave][1] = e; }
    __syncthreads();
    if (threadIdx.x == 0) {
        double A    = sacc[0][0] + sacc[1][0] + sacc[2][0] + sacc[3][0];
        double Esum = sacc[0][1] + sacc[1][1] + sacc[2][1] + sacc[3][1];
        double M = (double)OH * (double)OW;
        double loss_xy = A / M;
        double loss_e  = fabs(Esum / ((double)GH * (double)GW) - 1.0) / 100.0;
        out[0] = (float)(loss_xy + loss_e);
    }
}

extern "C" void kernel_launch(void* const* d_in, const int* in_sizes, int n_in,
                              void* d_out, int out_size, void* d_ws, size_t ws_size,
                              hipStream_t stream) {
    const float* E      = (const float*)d_in[0];
    const float* v      = (const float*)d_in[1];
    const float* strain = (const float*)d_in[2];
    float* out = (float*)d_out;
    float2* partials = (float2*)d_ws;

    hipLaunchKernelGGL(stencil_kernel, dim3(NBLOCKS), dim3(256), 0, stream,
                       E, v, strain, partials);
    hipLaunchKernelGGL(finalize_kernel, dim3(1), dim3(256), 0, stream, partials, out);
}